// Round 6
// baseline (463.855 us; speedup 1.0000x reference)
//
#include <hip/hip_runtime.h>
#include <hip/hip_cooperative_groups.h>

#define TDIM 2048

typedef __bf16 bf16_t;
typedef bf16_t bf16x8 __attribute__((ext_vector_type(8)));
typedef float f32x4 __attribute__((ext_vector_type(4)));
typedef unsigned short us8 __attribute__((ext_vector_type(8)));

__device__ __forceinline__ unsigned short f2bf(float x) {
  unsigned u = __builtin_bit_cast(unsigned, x);
  u += 0x7fffu + ((u >> 16) & 1u);            // round-to-nearest-even
  return (unsigned short)(u >> 16);
}

// async global->LDS, 16B per lane; lds base wave-uniform (HW adds lane*16)
__device__ __forceinline__ void gl_lds16(const unsigned short* g, unsigned short* l) {
  __builtin_amdgcn_global_load_lds(
      (const __attribute__((address_space(1))) unsigned int*)g,
      (__attribute__((address_space(3))) unsigned int*)l, 16, 0, 0);
}

// ---------------------------------------------------------------------------
// Single cooperative kernel. grid (32 tb, 8 b) = 256 wgs x 1024 thr (16 waves).
//  A: BN-fold W -> effWf (frag order) + effb          [wgs 0..12]
//  B: QKV GEMM (all 384 oc per wg, x read once)       -> vv / kTs / qTs
//  C: QK^T scores + row max; b==0 wgs emit denom0 (ref's [0]-broadcast bug)
//  D: normalize, P scatter, PV (V direct from global), residual epilogue
// ---------------------------------------------------------------------------
__global__ __launch_bounds__(1024, 4) void k_fused(
    const float* __restrict__ x,
    const float* __restrict__ kW, const float* __restrict__ kb,
    const float* __restrict__ kg, const float* __restrict__ kbe,
    const float* __restrict__ kmu, const float* __restrict__ kva,
    const float* __restrict__ qW, const float* __restrict__ qb,
    const float* __restrict__ qg, const float* __restrict__ qbe,
    const float* __restrict__ qmu, const float* __restrict__ qva,
    const float* __restrict__ vW, const float* __restrict__ vb,
    const float* __restrict__ vg, const float* __restrict__ vbe,
    const float* __restrict__ vmu, const float* __restrict__ vva,
    unsigned short* __restrict__ vv,
    unsigned short* __restrict__ kTs,
    unsigned short* __restrict__ qTs,
    float* __restrict__ denom0,
    unsigned short* __restrict__ effWf,
    float* __restrict__ effb,
    float* __restrict__ out)
{
  const int tx = blockIdx.x, b = blockIdx.y;
  const int tid = threadIdx.x;
  const int lane = tid & 63, w = tid >> 6;       // 16 waves
  const int m = lane & 15, quad = lane >> 4;
  const int t0 = tx * 64;

  // phase B: Wb 24576 | Xs 4608 ; phase C: Qs 4096 | Ks 20480 ; phase D: Ps 22016
  __shared__ unsigned short SM[29184];
  __shared__ float pmaxs[256];                   // [half 4][row 64]
  __shared__ float psums[256];

  cooperative_groups::grid_group gg = cooperative_groups::this_grid();

  // ======== Phase A: weight fold ========
  {
    int gtid = (b * 32 + tx) * 1024 + tid;
    if (gtid < 12288) {
      int idx = gtid >> 10, f = gtid & 1023;     // idx = gid*4+cc
      int gid = idx >> 2, cc = idx & 3;
      int ocblk = f >> 7, cblk = (f >> 4) & 7, mm = f & 15;
      int G = gid * 128 + ocblk * 16 + mm;
      const float* Wp = (G < 64) ? (kW + G * 256)
                       : (G < 128) ? (qW + (G - 64) * 256)
                                   : (vW + (G - 128) * 256);
      float ggn = (G < 64) ? kg[G]  : (G < 128) ? qg[G - 64]  : vg[G - 128];
      float vr  = (G < 64) ? kva[G] : (G < 128) ? qva[G - 64] : vva[G - 128];
      float inv = ggn * rsqrtf(vr + 1e-5f);
      int c = cc * 64 + cblk * 8;
      float4 a = *(const float4*)(Wp + c);
      float4 bq = *(const float4*)(Wp + c + 4);
      ushort4 lo, hi;
      lo.x = f2bf(a.x * inv);  lo.y = f2bf(a.y * inv);
      lo.z = f2bf(a.z * inv);  lo.w = f2bf(a.w * inv);
      hi.x = f2bf(bq.x * inv); hi.y = f2bf(bq.y * inv);
      hi.z = f2bf(bq.z * inv); hi.w = f2bf(bq.w * inv);
      unsigned short* dst = effWf + (size_t)idx * 8192 + f * 8;
      *(ushort4*)dst = lo;
      *(ushort4*)(dst + 4) = hi;
    } else if (gtid < 12672) {
      int G = gtid - 12288;
      float ggn = (G < 64) ? kg[G]  : (G < 128) ? qg[G - 64]  : vg[G - 128];
      float vr  = (G < 64) ? kva[G] : (G < 128) ? qva[G - 64] : vva[G - 128];
      float bb  = (G < 64) ? kb[G]  : (G < 128) ? qb[G - 64]  : vb[G - 128];
      float mm  = (G < 64) ? kmu[G] : (G < 128) ? qmu[G - 64] : vmu[G - 128];
      float be  = (G < 64) ? kbe[G] : (G < 128) ? qbe[G - 64] : vbe[G - 128];
      float inv = ggn * rsqrtf(vr + 1e-5f);
      effb[G] = (bb - mm) * inv + be;
    }
  }
  __threadfence();
  gg.sync();

  // ======== Phase B: QKV GEMM (64 t x 384 oc x 256 c) ========
  {
    unsigned short* Wb = SM;                     // 384oc x 64c chunk, frag order
    unsigned short* Xs = SM + 24576;             // 64t x 64c, XOR-swizzled
    const int ow = w & 7, th = w >> 3;
    const int cg = tid >> 6;                     // 16 c-groups of 4
    const float* xb = x + (size_t)b * 256 * TDIM + t0 + (tid & 63);
    float xr[4];
    const f32x4 fz = {0.f, 0.f, 0.f, 0.f};
    f32x4 acc[3][2];
#pragma unroll
    for (int j = 0; j < 3; ++j) { acc[j][0] = fz; acc[j][1] = fz; }

#pragma unroll
    for (int j = 0; j < 4; ++j) xr[j] = xb[(size_t)(cg * 4 + j) * TDIM];

    for (int cc = 0; cc < 4; ++cc) {
      __syncthreads();                           // (A) prev MFMA reads done
#pragma unroll
      for (int it = 0; it < 3; ++it) {           // stage W(cc): 3072 16B chunks
        int j = it * 1024 + tid;
        int rg = j >> 10, jj = j & 1023;
        gl_lds16(effWf + (size_t)(rg * 4 + cc) * 8192 + jj * 8,
                 &Wb[(it * 1024 + w * 64) * 8]);
      }
      {                                          // Xs store (transpose+convert)
        int t = tid & 63;
        int cb4 = cg * 4;
        int swz = (((cb4 >> 3) ^ (t >> 3)) << 3) | (cb4 & 7);
        ushort4 s4;
        s4.x = f2bf(xr[0]); s4.y = f2bf(xr[1]);
        s4.z = f2bf(xr[2]); s4.w = f2bf(xr[3]);
        *(ushort4*)&Xs[t * 72 + swz] = s4;
      }
      if (cc < 3) {
#pragma unroll
        for (int j = 0; j < 4; ++j)
          xr[j] = xb[(size_t)((cc + 1) * 64 + cg * 4 + j) * TDIM];
      }
      __syncthreads();                           // (B) W glds + Xs drained
#pragma unroll
      for (int kk = 0; kk < 2; ++kk) {
        int cb = kk * 4 + quad;
        bf16x8 af[3], bfv[2];
#pragma unroll
        for (int j = 0; j < 3; ++j) {
          int ob = ow * 3 + j;                   // 0..23
          af[j] = *(const bf16x8*)&Wb[((ob >> 3) * 1024 + ((ob & 7) * 8 + cb) * 16 + m) * 8];
        }
#pragma unroll
        for (int nt = 0; nt < 2; ++nt) {
          int t = (th * 2 + nt) * 16 + m;
          bfv[nt] = *(const bf16x8*)&Xs[t * 72 + ((cb ^ (t >> 3)) << 3)];
        }
#pragma unroll
        for (int j = 0; j < 3; ++j)
#pragma unroll
          for (int nt = 0; nt < 2; ++nt)
            acc[j][nt] = __builtin_amdgcn_mfma_f32_16x16x32_bf16(af[j], bfv[nt], acc[j][nt], 0, 0, 0);
      }
    }
    // epilogue. D: row (oc) = quad*4+r, col (t) = m
#pragma unroll
    for (int j = 0; j < 3; ++j) {
      int ob = ow * 3 + j;
      int ocb = ob * 16 + quad * 4;
      float bia[4];
#pragma unroll
      for (int r = 0; r < 4; ++r) bia[r] = effb[ocb + r];
#pragma unroll
      for (int nt = 0; nt < 2; ++nt) {
        int t = t0 + (th * 2 + nt) * 16 + m;
        float y0 = fmaxf(acc[j][nt][0] + bia[0], 0.f);
        float y1 = fmaxf(acc[j][nt][1] + bia[1], 0.f);
        float y2 = fmaxf(acc[j][nt][2] + bia[2], 0.f);
        float y3 = fmaxf(acc[j][nt][3] + bia[3], 0.f);
        if (ob < 8) {                            // K (ob<4) or Q: pre-swizzled [b][t][64']
          ushort4 s4;
          s4.x = f2bf(y0); s4.y = f2bf(y1); s4.z = f2bf(y2); s4.w = f2bf(y3);
          int oc6 = ocb & 63;
          int col = (((oc6 >> 3) ^ (t & 7)) << 3) | (oc6 & 7);
          unsigned short* dst = ((ob < 4) ? kTs : qTs) + (size_t)(b * TDIM + t) * 64 + col;
          *(ushort4*)dst = s4;
        } else {                                 // V [b][c][t]
          int c = ocb - 128;
          vv[(size_t)(b * 256 + c + 0) * TDIM + t] = f2bf(y0);
          vv[(size_t)(b * 256 + c + 1) * TDIM + t] = f2bf(y1);
          vv[(size_t)(b * 256 + c + 2) * TDIM + t] = f2bf(y2);
          vv[(size_t)(b * 256 + c + 3) * TDIM + t] = f2bf(y3);
        }
      }
    }
  }
  __threadfence();
  gg.sync();

  // ======== Phase C: scores + maxes (+ denom0 from b==0 wgs) ========
  unsigned short* Qs = SM;
  unsigned short* Ks = SM + 4096;
  unsigned short* Ps = SM;
  {
    const unsigned short* qg = qTs + (size_t)(b * TDIM + t0) * 64;
    const unsigned short* kg = kTs + ((long)(b * TDIM + t0) - 256) * 64;  // finite garbage, masked
#pragma unroll
    for (int it = 0; it < 3; ++it) {
      int j = it * 1024 + tid;
      const unsigned short* g = (j < 512) ? qg + (size_t)j * 8
                                          : kg + (size_t)(j - 512) * 8;
      gl_lds16(g, &SM[(it * 1024 + w * 64) * 8]);
    }
  }
  __syncthreads();                               // staging drained

  const int rt = w & 3, half = w >> 2;           // 4 row-tiles x 4 s-quarters
  const int tw = t0 + rt * 16;
  const int j0 = (half == 0) ? 0 : (half == 1) ? 5 : (half == 2) ? 9 : 13;
  const int jn = (half == 0) ? 5 : 4;
  f32x4 sc[5];
  {
    int t = rt * 16 + m;
    bf16x8 qf0 = *(const bf16x8*)&Qs[t * 64 + ((quad ^ (t & 7)) << 3)];
    bf16x8 qf1 = *(const bf16x8*)&Qs[t * 64 + (((4 + quad) ^ (t & 7)) << 3)];
    const f32x4 fz = {0.f, 0.f, 0.f, 0.f};
#pragma unroll
    for (int jj = 0; jj < 5; ++jj)
      if (jj < jn) {
        int sr = 16 * (rt + j0 + jj) + m;
        f32x4 a = fz;
        bf16x8 kf0 = *(const bf16x8*)&Ks[sr * 64 + ((quad ^ (sr & 7)) << 3)];
        a = __builtin_amdgcn_mfma_f32_16x16x32_bf16(qf0, kf0, a, 0, 0, 0);
        bf16x8 kf1 = *(const bf16x8*)&Ks[sr * 64 + (((4 + quad) ^ (sr & 7)) << 3)];
        a = __builtin_amdgcn_mfma_f32_16x16x32_bf16(qf1, kf1, a, 0, 0, 0);
        sc[jj] = a;
      }
  }
  float mx[4] = {0.f, 0.f, 0.f, 0.f};
#pragma unroll
  for (int jj = 0; jj < 5; ++jj)
    if (jj < jn) {
#pragma unroll
      for (int r = 0; r < 4; ++r) {
        float v = sc[jj][r] * 0.125f;
        sc[jj][r] = v;
        int tg = tw + quad * 4 + r;
        int sg = t0 - 256 + 16 * (rt + j0 + jj) + m;
        if (sg >= 0 && sg <= tg && tg - sg < 256) mx[r] = fmaxf(mx[r], v);
      }
    }
#pragma unroll
  for (int d = 1; d < 16; d <<= 1)
#pragma unroll
    for (int r = 0; r < 4; ++r) mx[r] = fmaxf(mx[r], __shfl_xor(mx[r], d, 64));
  if (m == 0)
#pragma unroll
    for (int r = 0; r < 4; ++r) pmaxs[half * 64 + rt * 16 + quad * 4 + r] = mx[r];
  __syncthreads();

  float mxf[4];
#pragma unroll
  for (int r = 0; r < 4; ++r) {
    int row = rt * 16 + quad * 4 + r;
    mxf[r] = fmaxf(fmaxf(pmaxs[row], pmaxs[64 + row]),
                   fmaxf(pmaxs[128 + row], pmaxs[192 + row]));
  }
  if (b == 0) {                                  // the [0]-broadcast denominator
    float smv[4] = {0.f, 0.f, 0.f, 0.f};
#pragma unroll
    for (int jj = 0; jj < 5; ++jj)
      if (jj < jn) {
#pragma unroll
        for (int r = 0; r < 4; ++r) {
          int tg = tw + quad * 4 + r;
          int sg = t0 - 256 + 16 * (rt + j0 + jj) + m;
          if (sg >= 0 && sg <= tg && tg - sg < 256) smv[r] += __expf(sc[jj][r] - mxf[r]);
        }
      }
#pragma unroll
    for (int d = 1; d < 16; d <<= 1)
#pragma unroll
      for (int r = 0; r < 4; ++r) smv[r] += __shfl_xor(smv[r], d, 64);
    if (m == 0)
#pragma unroll
      for (int r = 0; r < 4; ++r) psums[half * 64 + rt * 16 + quad * 4 + r] = smv[r];
    __syncthreads();
    if (tid < 64)
      denom0[t0 + tid] = psums[tid] + psums[64 + tid] + psums[128 + tid] + psums[192 + tid];
  }
  __threadfence();
  gg.sync();

  // ======== Phase D: normalize + P scatter + PV + residual ========
  float rden[4];
#pragma unroll
  for (int r = 0; r < 4; ++r)
    rden[r] = 1.f / (denom0[tw + quad * 4 + r] + 1e-30f);
#pragma unroll
  for (int jj = 0; jj < 5; ++jj)
    if (jj < jn) {
#pragma unroll
      for (int r = 0; r < 4; ++r) {
        int tg = tw + quad * 4 + r;
        int sg = t0 - 256 + 16 * (rt + j0 + jj) + m;
        bool ib = (sg >= 0 && sg <= tg && tg - sg < 256);
        sc[jj][r] = ib ? __expf(sc[jj][r] - mxf[r]) * rden[r] : 0.f;
      }
    }

  // zero pads just outside each row-tile's scatter window
  if (half == 1 && rt > 0) {
    int row = rt * 16 + (lane >> 2), col = 16 * rt - 16 + (lane & 3) * 4;
    ushort4 z; z.x = 0; z.y = 0; z.z = 0; z.w = 0;
    *(ushort4*)&Ps[row * 344 + col] = z;
  }
  if (half == 2 && rt < 3) {
    int row = rt * 16 + (lane >> 2), col = 16 * rt + 272 + (lane & 3) * 4;
    ushort4 z; z.x = 0; z.y = 0; z.z = 0; z.w = 0;
    *(ushort4*)&Ps[row * 344 + col] = z;
  }
  // scatter normalized P (rows rt*16+quad*4+r, cols 16*(rt+j0+jj)+m)
#pragma unroll
  for (int jj = 0; jj < 5; ++jj)
    if (jj < jn) {
      int col = 16 * (rt + j0 + jj) + m;
#pragma unroll
      for (int r = 0; r < 4; ++r)
        Ps[(rt * 16 + quad * 4 + r) * 344 + col] = f2bf(sc[jj][r]);
    }

  // V chunk-0 prefetch before the barrier
  const unsigned short* vrow = vv + (size_t)(b * 256 + w * 16 + m) * TDIM;
  us8 vreg = {0, 0, 0, 0, 0, 0, 0, 0};
  if (t0 >= 256) vreg = *(const us8*)(vrow + t0 - 256 + quad * 8);

  __syncthreads();                               // P visible

  // x-residual prefetch (overlaps PV)
  float4 xv[4];
#pragma unroll
  for (int mt = 0; mt < 4; ++mt) {
    int c = w * 16 + m;
    int t = t0 + mt * 16 + quad * 4;
    xv[mt] = *(const float4*)(x + (size_t)(b * 256 + c) * TDIM + t);
  }

  const f32x4 fz2 = {0.f, 0.f, 0.f, 0.f};
  f32x4 acc2[4] = {fz2, fz2, fz2, fz2};
#pragma unroll
  for (int chunk = 0; chunk < 10; ++chunk) {
    us8 vn = {0, 0, 0, 0, 0, 0, 0, 0};
    if (chunk < 9) {
      int sbase = t0 - 256 + (chunk + 1) * 32;
      if (sbase >= 0) vn = *(const us8*)(vrow + sbase + quad * 8);
    }
    bf16x8 bfr = __builtin_bit_cast(bf16x8, vreg);
#pragma unroll
    for (int mt = 0; mt < 4; ++mt) {
      const int cs = mt >> 1;
      if (chunk >= cs && chunk <= cs + 8) {
        bf16x8 af = *(const bf16x8*)&Ps[(mt * 16 + m) * 344 + chunk * 32 + quad * 8];
        acc2[mt] = __builtin_amdgcn_mfma_f32_16x16x32_bf16(af, bfr, acc2[mt], 0, 0, 0);
      }
    }
    vreg = vn;
  }

  // epilogue: out = x + O^T.  D: col (c) = m, row (t) = quad*4+r
#pragma unroll
  for (int mt = 0; mt < 4; ++mt) {
    int c = w * 16 + m;
    int t = t0 + mt * 16 + quad * 4;
    size_t off = (size_t)(b * 256 + c) * TDIM + t;
    float4 o;
    o.x = xv[mt].x + acc2[mt][0];
    o.y = xv[mt].y + acc2[mt][1];
    o.z = xv[mt].z + acc2[mt][2];
    o.w = xv[mt].w + acc2[mt][3];
    *(float4*)(out + off) = o;
  }
}

// ---------------------------------------------------------------------------
extern "C" void kernel_launch(void* const* d_in, const int* in_sizes, int n_in,
                              void* d_out, int out_size, void* d_ws, size_t ws_size,
                              hipStream_t stream) {
  const float* x   = (const float*)d_in[0];
  const float* kW  = (const float*)d_in[1];
  const float* kb  = (const float*)d_in[2];
  const float* kg  = (const float*)d_in[3];
  const float* kbe = (const float*)d_in[4];
  const float* kmu = (const float*)d_in[5];
  const float* kva = (const float*)d_in[6];
  const float* qW  = (const float*)d_in[7];
  const float* qb  = (const float*)d_in[8];
  const float* qg  = (const float*)d_in[9];
  const float* qbe = (const float*)d_in[10];
  const float* qmu = (const float*)d_in[11];
  const float* qva = (const float*)d_in[12];
  const float* vW  = (const float*)d_in[13];
  const float* vb  = (const float*)d_in[14];
  const float* vg  = (const float*)d_in[15];
  const float* vbe = (const float*)d_in[16];
  const float* vmu = (const float*)d_in[17];
  const float* vva = (const float*)d_in[18];

  unsigned short* vv  = (unsigned short*)d_ws;                  // 8 MB
  unsigned short* kTs = vv + (size_t)8 * 256 * TDIM;            // 2 MB
  unsigned short* qTs = kTs + (size_t)8 * TDIM * 64;            // 2 MB
  float* denom0 = (float*)(qTs + (size_t)8 * TDIM * 64);        // 8 KB
  unsigned short* effWf = (unsigned short*)(denom0 + 2048);     // 192 KB
  float* effb = (float*)(effWf + 12 * 8192);                    // 1.5 KB
  float* outp = (float*)d_out;

  void* args[] = {
    (void*)&x,
    (void*)&kW, (void*)&kb, (void*)&kg, (void*)&kbe, (void*)&kmu, (void*)&kva,
    (void*)&qW, (void*)&qb, (void*)&qg, (void*)&qbe, (void*)&qmu, (void*)&qva,
    (void*)&vW, (void*)&vb, (void*)&vg, (void*)&vbe, (void*)&vmu, (void*)&vva,
    (void*)&vv, (void*)&kTs, (void*)&qTs, (void*)&denom0,
    (void*)&effWf, (void*)&effb, (void*)&outp
  };
  hipLaunchCooperativeKernel((const void*)k_fused, dim3(32, 8), dim3(1024),
                             args, 0, stream);
}

// Round 7
// 136.399 us; speedup vs baseline: 3.4007x; 3.4007x over previous
//
#include <hip/hip_runtime.h>

#define TDIM 2048

typedef __bf16 bf16_t;
typedef bf16_t bf16x8 __attribute__((ext_vector_type(8)));
typedef float f32x4 __attribute__((ext_vector_type(4)));
typedef unsigned short us8 __attribute__((ext_vector_type(8)));

__device__ __forceinline__ unsigned short f2bf(float x) {
  unsigned u = __builtin_bit_cast(unsigned, x);
  u += 0x7fffu + ((u >> 16) & 1u);            // round-to-nearest-even
  return (unsigned short)(u >> 16);
}

// async global->LDS, 16B per lane; lds base wave-uniform (HW adds lane*16)
__device__ __forceinline__ void gl_lds16(const unsigned short* g, unsigned short* l) {
  __builtin_amdgcn_global_load_lds(
      (const __attribute__((address_space(1))) unsigned int*)g,
      (__attribute__((address_space(3))) unsigned int*)l, 16, 0, 0);
}

// ---------------------------------------------------------------------------
// K0: BN-fold weights -> effWf bf16 in MFMA-fragment order. grid 12 x 256.
// ---------------------------------------------------------------------------
__global__ __launch_bounds__(256) void k_prepw(
    const float* __restrict__ kW, const float* __restrict__ kb,
    const float* __restrict__ kg, const float* __restrict__ kbe,
    const float* __restrict__ kmu, const float* __restrict__ kva,
    const float* __restrict__ qW, const float* __restrict__ qb,
    const float* __restrict__ qg, const float* __restrict__ qbe,
    const float* __restrict__ qmu, const float* __restrict__ qva,
    const float* __restrict__ vW, const float* __restrict__ vb,
    const float* __restrict__ vg, const float* __restrict__ vbe,
    const float* __restrict__ vmu, const float* __restrict__ vva,
    unsigned short* __restrict__ effWf,
    float* __restrict__ effb)
{
  const int idx = blockIdx.x;            // gid*4 + cc
  const int tid = threadIdx.x;
  const int gid = idx >> 2, cc = idx & 3;
  unsigned short* dst = effWf + (size_t)idx * 8192;
#pragma unroll
  for (int pass = 0; pass < 4; ++pass) {
    int f = pass * 256 + tid;
    int ocblk = f >> 7, cblk = (f >> 4) & 7, m = f & 15;
    int G = gid * 128 + ocblk * 16 + m;
    const float* Wp = (G < 64) ? (kW + G * 256)
                     : (G < 128) ? (qW + (G - 64) * 256)
                                 : (vW + (G - 128) * 256);
    float gg = (G < 64) ? kg[G]  : (G < 128) ? qg[G - 64]  : vg[G - 128];
    float vr = (G < 64) ? kva[G] : (G < 128) ? qva[G - 64] : vva[G - 128];
    float inv = gg * rsqrtf(vr + 1e-5f);
    int c = cc * 64 + cblk * 8;
    float4 a = *(const float4*)(Wp + c);
    float4 bq = *(const float4*)(Wp + c + 4);
    ushort4 lo, hi;
    lo.x = f2bf(a.x * inv);  lo.y = f2bf(a.y * inv);
    lo.z = f2bf(a.z * inv);  lo.w = f2bf(a.w * inv);
    hi.x = f2bf(bq.x * inv); hi.y = f2bf(bq.y * inv);
    hi.z = f2bf(bq.z * inv); hi.w = f2bf(bq.w * inv);
    *(ushort4*)(dst + f * 8) = lo;
    *(ushort4*)(dst + f * 8 + 4) = hi;
  }
  if (idx == 0) {
    for (int G = tid; G < 384; G += 256) {
      float gg = (G < 64) ? kg[G]  : (G < 128) ? qg[G - 64]  : vg[G - 128];
      float vr = (G < 64) ? kva[G] : (G < 128) ? qva[G - 64] : vva[G - 128];
      float bb = (G < 64) ? kb[G]  : (G < 128) ? qb[G - 64]  : vb[G - 128];
      float mm = (G < 64) ? kmu[G] : (G < 128) ? qmu[G - 64] : vmu[G - 128];
      float be = (G < 64) ? kbe[G] : (G < 128) ? qbe[G - 64] : vbe[G - 128];
      float inv = gg * rsqrtf(vr + 1e-5f);
      effb[G] = (bb - mm) * inv + be;
    }
  }
}

// ---------------------------------------------------------------------------
// K1: QKV GEMM. W via global_load_lds (frag order), x transposed inline.
// grid (32 tb, 3 gid, 8 b), block 256 (4 waves), 3 wg/CU.
//   gid 0 -> K/Q transposed+pre-swizzled [b][t][64']; gid 1,2 -> V [b][c][t]
// ---------------------------------------------------------------------------
__global__ __launch_bounds__(256, 3) void k_qkv(
    const unsigned short* __restrict__ effWf,
    const float* __restrict__ effb,
    const float* __restrict__ x,
    unsigned short* __restrict__ vv,
    unsigned short* __restrict__ kTs,
    unsigned short* __restrict__ qTs)
{
  const int tb = blockIdx.x, gid = blockIdx.y, b = blockIdx.z;
  const int tid = threadIdx.x;
  const int lane = tid & 63, wv = tid >> 6;
  const int m = lane & 15, quad = lane >> 4;
  const int t0 = tb * 64;

  __shared__ unsigned short Wb[2][8192];   // 128oc x 64c chunk, frag order
  __shared__ unsigned short Xs[4608];      // 64t x 64c, XOR-swizzled (72 pitch)
  __shared__ float effbs[128];

  if (tid < 128) effbs[tid] = effb[gid * 128 + tid];

  const unsigned short* wbase = effWf + (size_t)gid * 32768;
  const float* xb = x + (size_t)b * 256 * TDIM + t0 + lane;

  float xr[16];

  auto stageW = [&](int cc, int bufi) {
    const unsigned short* ws = wbase + cc * 8192;
#pragma unroll
    for (int i = 0; i < 4; ++i) {
      int ii = wv * 4 + i;
      gl_lds16(ws + (ii * 64 + lane) * 8, &Wb[bufi][ii * 512]);
    }
  };
  auto loadX = [&](int cc) {
#pragma unroll
    for (int p = 0; p < 4; ++p)
#pragma unroll
      for (int j = 0; j < 4; ++j) {
        int c = cc * 64 + p * 16 + wv * 4 + j;
        xr[p * 4 + j] = xb[(size_t)c * TDIM];
      }
  };

  const f32x4 fz = {0.f, 0.f, 0.f, 0.f};
  f32x4 acc[2][4];
#pragma unroll
  for (int i = 0; i < 2; ++i)
#pragma unroll
    for (int j = 0; j < 4; ++j) acc[i][j] = fz;

  stageW(0, 0);
  loadX(0);
  for (int cc = 0; cc < 4; ++cc) {
    __syncthreads();                 // drains W(cc) glds; Xs WAR safe
#pragma unroll
    for (int p = 0; p < 4; ++p) {
      int cb4 = p * 16 + wv * 4;
      int swz = (((cb4 >> 3) ^ (lane >> 3)) << 3) | (cb4 & 7);
      ushort4 s4;
      s4.x = f2bf(xr[p * 4 + 0]); s4.y = f2bf(xr[p * 4 + 1]);
      s4.z = f2bf(xr[p * 4 + 2]); s4.w = f2bf(xr[p * 4 + 3]);
      *(ushort4*)&Xs[lane * 72 + swz] = s4;
    }
    if (cc < 3) { stageW(cc + 1, (cc + 1) & 1); loadX(cc + 1); }
    __syncthreads();                 // Xs visible
    const unsigned short* Wc = Wb[cc & 1];
#pragma unroll
    for (int kk = 0; kk < 2; ++kk) {
      int cb = kk * 4 + quad;
      bf16x8 af[2], bfv[4];
#pragma unroll
      for (int mt = 0; mt < 2; ++mt)
        af[mt] = *(const bf16x8*)&Wc[(((wv * 2 + mt) * 8 + cb) * 16 + m) * 8];
#pragma unroll
      for (int nt = 0; nt < 4; ++nt) {
        int t = nt * 16 + m;
        bfv[nt] = *(const bf16x8*)&Xs[t * 72 + ((cb ^ (t >> 3)) << 3)];
      }
#pragma unroll
      for (int mt = 0; mt < 2; ++mt)
#pragma unroll
        for (int nt = 0; nt < 4; ++nt)
          acc[mt][nt] = __builtin_amdgcn_mfma_f32_16x16x32_bf16(af[mt], bfv[nt], acc[mt][nt], 0, 0, 0);
    }
  }

  // epilogue. D layout: row (oc) = quad*4+r, col (t) = m
  if (gid == 0) {
#pragma unroll
    for (int mt = 0; mt < 2; ++mt)
#pragma unroll
      for (int nt = 0; nt < 4; ++nt) {
        int ocl = wv * 32 + mt * 16 + quad * 4;
        int t = t0 + nt * 16 + m;
        ushort4 s4;
        s4.x = f2bf(fmaxf(acc[mt][nt][0] + effbs[ocl + 0], 0.f));
        s4.y = f2bf(fmaxf(acc[mt][nt][1] + effbs[ocl + 1], 0.f));
        s4.z = f2bf(fmaxf(acc[mt][nt][2] + effbs[ocl + 2], 0.f));
        s4.w = f2bf(fmaxf(acc[mt][nt][3] + effbs[ocl + 3], 0.f));
        if (ocl < 64) {
          int col = (((ocl >> 3) ^ (t & 7)) << 3) | (ocl & 7);
          *(ushort4*)(kTs + ((size_t)(b * TDIM + t)) * 64 + col) = s4;
        } else {
          int oq = ocl - 64;
          int col = (((oq >> 3) ^ (t & 7)) << 3) | (oq & 7);
          *(ushort4*)(qTs + ((size_t)(b * TDIM + t)) * 64 + col) = s4;
        }
      }
  } else {
#pragma unroll
    for (int mt = 0; mt < 2; ++mt)
#pragma unroll
      for (int nt = 0; nt < 4; ++nt)
#pragma unroll
        for (int r = 0; r < 4; ++r) {
          int ocl = wv * 32 + mt * 16 + quad * 4 + r;
          float y = fmaxf(acc[mt][nt][r] + effbs[ocl], 0.f);
          int c = (gid - 1) * 128 + ocl;
          int t = t0 + nt * 16 + m;
          vv[(size_t)(b * 256 + c) * TDIM + t] = f2bf(y);
        }
  }
}

// ---------------------------------------------------------------------------
// K2: batch-0 row denominators (the reference's [0]-broadcast bug).
// grid 128 (16 rows each), block 512 (8 waves split the 17 s-tiles).
// ---------------------------------------------------------------------------
__global__ __launch_bounds__(512, 1) void k_denom(
    const unsigned short* __restrict__ kTs,
    const unsigned short* __restrict__ qTs,
    float* __restrict__ denom0)
{
  const int t0d = blockIdx.x * 16;
  const int tid = threadIdx.x;
  const int lane = tid & 63, w = tid >> 6;
  const int m = lane & 15, quad = lane >> 4;

  __shared__ unsigned short S[18432];     // Qs 16x64 | Ks 272x64
  unsigned short* Qs = S;
  unsigned short* Ks = S + 1024;
  __shared__ float pmaxs[8][16];
  __shared__ float psums[8][16];

  {
    const unsigned short* qg = qTs + (size_t)t0d * 64;
    const unsigned short* kg = kTs + ((long)t0d - 256) * 64;  // finite garbage, masked
#pragma unroll
    for (int it = 0; it < 5; ++it) {
      int j = it * 512 + tid;
      if (j < 2304) {
        const unsigned short* g = (j < 128) ? (qg + j * 8) : (kg + (size_t)(j - 128) * 8);
        gl_lds16(g, &S[(it * 512 + w * 64) * 8]);
      }
    }
  }
  __syncthreads();

  const int jn = (w == 0) ? 3 : 2;
  f32x4 sc[3];
  {
    int t = m;
    bf16x8 qf0 = *(const bf16x8*)&Qs[t * 64 + ((quad ^ (t & 7)) << 3)];
    bf16x8 qf1 = *(const bf16x8*)&Qs[t * 64 + (((4 + quad) ^ (t & 7)) << 3)];
    const f32x4 fz = {0.f, 0.f, 0.f, 0.f};
#pragma unroll
    for (int jj = 0; jj < 3; ++jj) {
      if (jj < jn) {
        int j = w + jj * 8;
        int sr = 16 * j + m;
        f32x4 a = fz;
        bf16x8 kf0 = *(const bf16x8*)&Ks[sr * 64 + ((quad ^ (sr & 7)) << 3)];
        a = __builtin_amdgcn_mfma_f32_16x16x32_bf16(qf0, kf0, a, 0, 0, 0);
        bf16x8 kf1 = *(const bf16x8*)&Ks[sr * 64 + (((4 + quad) ^ (sr & 7)) << 3)];
        a = __builtin_amdgcn_mfma_f32_16x16x32_bf16(qf1, kf1, a, 0, 0, 0);
        sc[jj] = a;
      }
    }
  }

  float mx[4] = {0.f, 0.f, 0.f, 0.f};
#pragma unroll
  for (int jj = 0; jj < 3; ++jj)
    if (jj < jn) {
      int j = w + jj * 8;
#pragma unroll
      for (int r = 0; r < 4; ++r) {
        float v = sc[jj][r] * 0.125f;
        sc[jj][r] = v;
        int tg = t0d + quad * 4 + r;
        int sg = t0d - 256 + 16 * j + m;
        if (sg >= 0 && sg <= tg && tg - sg < 256) mx[r] = fmaxf(mx[r], v);
      }
    }
#pragma unroll
  for (int d = 1; d < 16; d <<= 1)
#pragma unroll
    for (int r = 0; r < 4; ++r) mx[r] = fmaxf(mx[r], __shfl_xor(mx[r], d, 64));
  if (m == 0)
#pragma unroll
    for (int r = 0; r < 4; ++r) pmaxs[w][quad * 4 + r] = mx[r];
  __syncthreads();

  float mxf[4];
#pragma unroll
  for (int r = 0; r < 4; ++r) {
    float v = pmaxs[0][quad * 4 + r];
#pragma unroll
    for (int ww = 1; ww < 8; ++ww) v = fmaxf(v, pmaxs[ww][quad * 4 + r]);
    mxf[r] = v;
  }
  float sm[4] = {0.f, 0.f, 0.f, 0.f};
#pragma unroll
  for (int jj = 0; jj < 3; ++jj)
    if (jj < jn) {
      int j = w + jj * 8;
#pragma unroll
      for (int r = 0; r < 4; ++r) {
        int tg = t0d + quad * 4 + r;
        int sg = t0d - 256 + 16 * j + m;
        if (sg >= 0 && sg <= tg && tg - sg < 256) sm[r] += __expf(sc[jj][r] - mxf[r]);
      }
    }
#pragma unroll
  for (int d = 1; d < 16; d <<= 1)
#pragma unroll
    for (int r = 0; r < 4; ++r) sm[r] += __shfl_xor(sm[r], d, 64);
  if (m == 0)
#pragma unroll
    for (int r = 0; r < 4; ++r) psums[w][quad * 4 + r] = sm[r];
  __syncthreads();

  if (tid < 16) {
    float s = 0.f;
#pragma unroll
    for (int ww = 0; ww < 8; ++ww) s += psums[ww][tid];
    denom0[t0d + tid] = s;
  }
}

// ---------------------------------------------------------------------------
// K3: banded attention + residual, merged channels, 32-ROW TILES.
// grid (64 tb, 8 b) = 512 wgs (2 wg/CU, 16 waves/CU), block 512 (8 waves).
// wave = (rt = w&1 row-tile, part = w>>2 j-quarter); PV: wave owns 32-c strip.
// ---------------------------------------------------------------------------
__global__ __launch_bounds__(512, 4) void k_attn(
    const float* __restrict__ x,
    const unsigned short* __restrict__ vv,
    const unsigned short* __restrict__ kTs,
    const unsigned short* __restrict__ qTs,
    const float* __restrict__ denom0,
    float* __restrict__ out)
{
  const int tb = blockIdx.x, b = blockIdx.y;
  const int tid = threadIdx.x;
  const int lane = tid & 63, w = tid >> 6;
  const int m = lane & 15, quad = lane >> 4;
  const int t0 = tb * 32;

  // phase 1: Qs 32x64 (2048) + Ks 288x64 (18432) = 20480 shorts (40 KB)
  // phase 2: Ps 32x296 (9472 shorts) aliases the same block
  __shared__ unsigned short SM[20480];
  __shared__ float pmaxs[4][32];
  unsigned short* Qs = SM;
  unsigned short* Ks = SM + 2048;
  unsigned short* Ps = SM;

  {
    const unsigned short* qg = qTs + (size_t)(b * TDIM + t0) * 64;
    const unsigned short* kg = kTs + ((long)(b * TDIM + t0) - 256) * 64;  // finite garbage, masked
#pragma unroll
    for (int it = 0; it < 5; ++it) {
      int j = it * 512 + tid;          // 0..2559
      const unsigned short* g = (j < 256) ? qg + (size_t)j * 8
                                          : kg + (size_t)(j - 256) * 8;
      gl_lds16(g, &SM[(it * 512 + w * 64) * 8]);
    }
  }
  const int rt = w & 1, part = w >> 1;           // 2 row-tiles x 4 j-quarters
  const int tw = t0 + rt * 16;
  float dval[4];
#pragma unroll
  for (int r = 0; r < 4; ++r) dval[r] = denom0[tw + quad * 4 + r];
  __syncthreads();                               // B1: staging drained

  // j-tiles for row-tile rt: absolute tiles rt+jj, jj in 0..16 (17 tiles)
  const int j0 = (part == 0) ? 0 : (part == 1) ? 5 : (part == 2) ? 9 : 13;
  const int jn = (part == 0) ? 5 : 4;
  f32x4 sc[5];
  {
    int t = rt * 16 + m;
    bf16x8 qf0 = *(const bf16x8*)&Qs[t * 64 + ((quad ^ (t & 7)) << 3)];
    bf16x8 qf1 = *(const bf16x8*)&Qs[t * 64 + (((4 + quad) ^ (t & 7)) << 3)];
    const f32x4 fz = {0.f, 0.f, 0.f, 0.f};
#pragma unroll
    for (int jj = 0; jj < 5; ++jj)
      if (jj < jn) {
        int sr = 16 * (rt + j0 + jj) + m;
        f32x4 a = fz;
        bf16x8 kf0 = *(const bf16x8*)&Ks[sr * 64 + ((quad ^ (sr & 7)) << 3)];
        a = __builtin_amdgcn_mfma_f32_16x16x32_bf16(qf0, kf0, a, 0, 0, 0);
        bf16x8 kf1 = *(const bf16x8*)&Ks[sr * 64 + (((4 + quad) ^ (sr & 7)) << 3)];
        a = __builtin_amdgcn_mfma_f32_16x16x32_bf16(qf1, kf1, a, 0, 0, 0);
        sc[jj] = a;
      }
  }

  float mx[4] = {0.f, 0.f, 0.f, 0.f};
#pragma unroll
  for (int jj = 0; jj < 5; ++jj)
    if (jj < jn) {
#pragma unroll
      for (int r = 0; r < 4; ++r) {
        float v = sc[jj][r] * 0.125f;
        sc[jj][r] = v;
        int tg = tw + quad * 4 + r;
        int sg = t0 - 256 + 16 * (rt + j0 + jj) + m;
        if (sg >= 0 && sg <= tg && tg - sg < 256) mx[r] = fmaxf(mx[r], v);
      }
    }
#pragma unroll
  for (int d = 1; d < 16; d <<= 1)
#pragma unroll
    for (int r = 0; r < 4; ++r) mx[r] = fmaxf(mx[r], __shfl_xor(mx[r], d, 64));
  if (m == 0)
#pragma unroll
    for (int r = 0; r < 4; ++r) pmaxs[part][rt * 16 + quad * 4 + r] = mx[r];

  __syncthreads();                               // B2: frag reads done + pmax visible

  float mxf[4], rden[4];
#pragma unroll
  for (int r = 0; r < 4; ++r) {
    int row = rt * 16 + quad * 4 + r;
    mxf[r] = fmaxf(fmaxf(pmaxs[0][row], pmaxs[1][row]),
                   fmaxf(pmaxs[2][row], pmaxs[3][row]));
    rden[r] = 1.f / (dval[r] + 1e-30f);
  }
#pragma unroll
  for (int jj = 0; jj < 5; ++jj)
    if (jj < jn) {
#pragma unroll
      for (int r = 0; r < 4; ++r) {
        int tg = tw + quad * 4 + r;
        int sg = t0 - 256 + 16 * (rt + j0 + jj) + m;
        bool ib = (sg >= 0 && sg <= tg && tg - sg < 256);
        sc[jj][r] = ib ? __expf(sc[jj][r] - mxf[r]) * rden[r] : 0.f;
      }
    }

  // zero pads just outside each row-tile's scatter window:
  //   rt0 covers cols 0..271 -> pad 272..287 ; rt1 covers 16..287 -> pad 0..15
  if (part == 1) {
    int row = rt * 16 + (lane >> 2);
    int col = (rt == 0) ? (272 + (lane & 3) * 4) : ((lane & 3) * 4);
    ushort4 z; z.x = 0; z.y = 0; z.z = 0; z.w = 0;
    *(ushort4*)&Ps[row * 296 + col] = z;
  }
  // scatter normalized P (rows rt*16+quad*4+r, cols 16*(rt+j0+jj)+m)
#pragma unroll
  for (int jj = 0; jj < 5; ++jj)
    if (jj < jn) {
      int col = 16 * (rt + j0 + jj) + m;
#pragma unroll
      for (int r = 0; r < 4; ++r)
        Ps[(rt * 16 + quad * 4 + r) * 296 + col] = f2bf(sc[jj][r]);
    }

  // V chunk-0 prefetch (both c-tiles) before the barrier
  const int cbase = w * 32;
  const unsigned short* vrow0 = vv + (size_t)(b * 256 + cbase + m) * TDIM;
  const unsigned short* vrow1 = vrow0 + (size_t)16 * TDIM;
  us8 vreg0 = {0, 0, 0, 0, 0, 0, 0, 0}, vreg1 = {0, 0, 0, 0, 0, 0, 0, 0};
  if (t0 >= 256) {
    vreg0 = *(const us8*)(vrow0 + t0 - 256 + quad * 8);
    vreg1 = *(const us8*)(vrow1 + t0 - 256 + quad * 8);
  }

  __syncthreads();                               // B3: P visible

  // x-residual prefetch (overlaps PV)
  float4 xv[2][2];
#pragma unroll
  for (int mt = 0; mt < 2; ++mt)
#pragma unroll
    for (int ct = 0; ct < 2; ++ct) {
      int c = cbase + ct * 16 + m;
      int t = t0 + mt * 16 + quad * 4;
      xv[mt][ct] = *(const float4*)(x + (size_t)(b * 256 + c) * TDIM + t);
    }

  // ---- PV: 9 chunks of 32 s; both row-tiles use all chunks (pads fix edges)
  const f32x4 fz = {0.f, 0.f, 0.f, 0.f};
  f32x4 acc[2][2];
  acc[0][0] = fz; acc[0][1] = fz; acc[1][0] = fz; acc[1][1] = fz;
#pragma unroll
  for (int chunk = 0; chunk < 9; ++chunk) {
    us8 vn0 = {0, 0, 0, 0, 0, 0, 0, 0}, vn1 = {0, 0, 0, 0, 0, 0, 0, 0};
    if (chunk < 8) {
      int sbase = t0 - 256 + (chunk + 1) * 32;
      if (sbase >= 0) {
        vn0 = *(const us8*)(vrow0 + sbase + quad * 8);
        vn1 = *(const us8*)(vrow1 + sbase + quad * 8);
      }
    }
    bf16x8 bfr0 = __builtin_bit_cast(bf16x8, vreg0);
    bf16x8 bfr1 = __builtin_bit_cast(bf16x8, vreg1);
#pragma unroll
    for (int mt = 0; mt < 2; ++mt) {
      bf16x8 af = *(const bf16x8*)&Ps[(mt * 16 + m) * 296 + chunk * 32 + quad * 8];
      acc[mt][0] = __builtin_amdgcn_mfma_f32_16x16x32_bf16(af, bfr0, acc[mt][0], 0, 0, 0);
      acc[mt][1] = __builtin_amdgcn_mfma_f32_16x16x32_bf16(af, bfr1, acc[mt][1], 0, 0, 0);
    }
    vreg0 = vn0; vreg1 = vn1;
  }

  // epilogue: out = x + O^T.  D: col (c) = m, row (t) = quad*4+r
#pragma unroll
  for (int mt = 0; mt < 2; ++mt)
#pragma unroll
    for (int ct = 0; ct < 2; ++ct) {
      int c = cbase + ct * 16 + m;
      int t = t0 + mt * 16 + quad * 4;
      size_t off = (size_t)(b * 256 + c) * TDIM + t;
      float4 o;
      o.x = xv[mt][ct].x + acc[mt][ct][0];
      o.y = xv[mt][ct].y + acc[mt][ct][1];
      o.z = xv[mt][ct].z + acc[mt][ct][2];
      o.w = xv[mt][ct].w + acc[mt][ct][3];
      *(float4*)(out + off) = o;
    }
}

// ---------------------------------------------------------------------------
extern "C" void kernel_launch(void* const* d_in, const int* in_sizes, int n_in,
                              void* d_out, int out_size, void* d_ws, size_t ws_size,
                              hipStream_t stream) {
  const float* x   = (const float*)d_in[0];
  const float* kW  = (const float*)d_in[1];
  const float* kb  = (const float*)d_in[2];
  const float* kg  = (const float*)d_in[3];
  const float* kbe = (const float*)d_in[4];
  const float* kmu = (const float*)d_in[5];
  const float* kva = (const float*)d_in[6];
  const float* qW  = (const float*)d_in[7];
  const float* qb  = (const float*)d_in[8];
  const float* qg  = (const float*)d_in[9];
  const float* qbe = (const float*)d_in[10];
  const float* qmu = (const float*)d_in[11];
  const float* qva = (const float*)d_in[12];
  const float* vW  = (const float*)d_in[13];
  const float* vb  = (const float*)d_in[14];
  const float* vg  = (const float*)d_in[15];
  const float* vbe = (const float*)d_in[16];
  const float* vmu = (const float*)d_in[17];
  const float* vva = (const float*)d_in[18];

  unsigned short* vv  = (unsigned short*)d_ws;                  // 8 MB
  unsigned short* kTs = vv + (size_t)8 * 256 * TDIM;            // 2 MB
  unsigned short* qTs = kTs + (size_t)8 * TDIM * 64;            // 2 MB
  float* denom0 = (float*)(qTs + (size_t)8 * TDIM * 64);        // 8 KB
  unsigned short* effWf = (unsigned short*)(denom0 + 2048);     // 192 KB
  float* effb = (float*)(effWf + 12 * 8192);                    // 1.5 KB
  float* outp = (float*)d_out;

  k_prepw<<<dim3(12), 256, 0, stream>>>(
      kW, kb, kg, kbe, kmu, kva,
      qW, qb, qg, qbe, qmu, qva,
      vW, vb, vg, vbe, vmu, vva, effWf, effb);
  k_qkv<<<dim3(32, 3, 8), 256, 0, stream>>>(effWf, effb, x, vv, kTs, qTs);
  k_denom<<<dim3(128), 512, 0, stream>>>(kTs, qTs, denom0);
  k_attn<<<dim3(64, 8), 512, 0, stream>>>(x, vv, kTs, qTs, denom0, outp);
}

// Round 8
// 130.987 us; speedup vs baseline: 3.5412x; 1.0413x over previous
//
#include <hip/hip_runtime.h>

#define TDIM 2048

typedef __bf16 bf16_t;
typedef bf16_t bf16x8 __attribute__((ext_vector_type(8)));
typedef float f32x4 __attribute__((ext_vector_type(4)));
typedef unsigned short us8 __attribute__((ext_vector_type(8)));

__device__ __forceinline__ unsigned short f2bf(float x) {
  unsigned u = __builtin_bit_cast(unsigned, x);
  u += 0x7fffu + ((u >> 16) & 1u);            // round-to-nearest-even
  return (unsigned short)(u >> 16);
}

// async global->LDS, 16B per lane; lds base wave-uniform (HW adds lane*16)
__device__ __forceinline__ void gl_lds16(const unsigned short* g, unsigned short* l) {
  __builtin_amdgcn_global_load_lds(
      (const __attribute__((address_space(1))) unsigned int*)g,
      (__attribute__((address_space(3))) unsigned int*)l, 16, 0, 0);
}

// ---------------------------------------------------------------------------
// K0: BN-fold weights -> effWf bf16 in MFMA-fragment order. grid 12 x 256.
// ---------------------------------------------------------------------------
__global__ __launch_bounds__(256) void k_prepw(
    const float* __restrict__ kW, const float* __restrict__ kb,
    const float* __restrict__ kg, const float* __restrict__ kbe,
    const float* __restrict__ kmu, const float* __restrict__ kva,
    const float* __restrict__ qW, const float* __restrict__ qb,
    const float* __restrict__ qg, const float* __restrict__ qbe,
    const float* __restrict__ qmu, const float* __restrict__ qva,
    const float* __restrict__ vW, const float* __restrict__ vb,
    const float* __restrict__ vg, const float* __restrict__ vbe,
    const float* __restrict__ vmu, const float* __restrict__ vva,
    unsigned short* __restrict__ effWf,
    float* __restrict__ effb)
{
  const int idx = blockIdx.x;            // gid*4 + cc
  const int tid = threadIdx.x;
  const int gid = idx >> 2, cc = idx & 3;
  unsigned short* dst = effWf + (size_t)idx * 8192;
#pragma unroll
  for (int pass = 0; pass < 4; ++pass) {
    int f = pass * 256 + tid;
    int ocblk = f >> 7, cblk = (f >> 4) & 7, m = f & 15;
    int G = gid * 128 + ocblk * 16 + m;
    const float* Wp = (G < 64) ? (kW + G * 256)
                     : (G < 128) ? (qW + (G - 64) * 256)
                                 : (vW + (G - 128) * 256);
    float gg = (G < 64) ? kg[G]  : (G < 128) ? qg[G - 64]  : vg[G - 128];
    float vr = (G < 64) ? kva[G] : (G < 128) ? qva[G - 64] : vva[G - 128];
    float inv = gg * rsqrtf(vr + 1e-5f);
    int c = cc * 64 + cblk * 8;
    float4 a = *(const float4*)(Wp + c);
    float4 bq = *(const float4*)(Wp + c + 4);
    ushort4 lo, hi;
    lo.x = f2bf(a.x * inv);  lo.y = f2bf(a.y * inv);
    lo.z = f2bf(a.z * inv);  lo.w = f2bf(a.w * inv);
    hi.x = f2bf(bq.x * inv); hi.y = f2bf(bq.y * inv);
    hi.z = f2bf(bq.z * inv); hi.w = f2bf(bq.w * inv);
    *(ushort4*)(dst + f * 8) = lo;
    *(ushort4*)(dst + f * 8 + 4) = hi;
  }
  if (idx == 0) {
    for (int G = tid; G < 384; G += 256) {
      float gg = (G < 64) ? kg[G]  : (G < 128) ? qg[G - 64]  : vg[G - 128];
      float vr = (G < 64) ? kva[G] : (G < 128) ? qva[G - 64] : vva[G - 128];
      float bb = (G < 64) ? kb[G]  : (G < 128) ? qb[G - 64]  : vb[G - 128];
      float mm = (G < 64) ? kmu[G] : (G < 128) ? qmu[G - 64] : vmu[G - 128];
      float be = (G < 64) ? kbe[G] : (G < 128) ? qbe[G - 64] : vbe[G - 128];
      float inv = gg * rsqrtf(vr + 1e-5f);
      effb[G] = (bb - mm) * inv + be;
    }
  }
}

// ---------------------------------------------------------------------------
// K1: QKV GEMM. W via global_load_lds (frag order), x transposed inline.
// grid (32 tb, 3 gid, 8 b), block 256 (4 waves), 3 wg/CU.
//   gid 0 -> K/Q transposed+pre-swizzled [b][t][64']; gid 1,2 -> V [b][c][t]
// ---------------------------------------------------------------------------
__global__ __launch_bounds__(256, 3) void k_qkv(
    const unsigned short* __restrict__ effWf,
    const float* __restrict__ effb,
    const float* __restrict__ x,
    unsigned short* __restrict__ vv,
    unsigned short* __restrict__ kTs,
    unsigned short* __restrict__ qTs)
{
  const int tb = blockIdx.x, gid = blockIdx.y, b = blockIdx.z;
  const int tid = threadIdx.x;
  const int lane = tid & 63, wv = tid >> 6;
  const int m = lane & 15, quad = lane >> 4;
  const int t0 = tb * 64;

  __shared__ unsigned short Wb[2][8192];   // 128oc x 64c chunk, frag order
  __shared__ unsigned short Xs[4608];      // 64t x 64c, XOR-swizzled (72 pitch)
  __shared__ float effbs[128];

  if (tid < 128) effbs[tid] = effb[gid * 128 + tid];

  const unsigned short* wbase = effWf + (size_t)gid * 32768;
  const float* xb = x + (size_t)b * 256 * TDIM + t0 + lane;

  float xr[16];

  auto stageW = [&](int cc, int bufi) {
    const unsigned short* ws = wbase + cc * 8192;
#pragma unroll
    for (int i = 0; i < 4; ++i) {
      int ii = wv * 4 + i;
      gl_lds16(ws + (ii * 64 + lane) * 8, &Wb[bufi][ii * 512]);
    }
  };
  auto loadX = [&](int cc) {
#pragma unroll
    for (int p = 0; p < 4; ++p)
#pragma unroll
      for (int j = 0; j < 4; ++j) {
        int c = cc * 64 + p * 16 + wv * 4 + j;
        xr[p * 4 + j] = xb[(size_t)c * TDIM];
      }
  };

  const f32x4 fz = {0.f, 0.f, 0.f, 0.f};
  f32x4 acc[2][4];
#pragma unroll
  for (int i = 0; i < 2; ++i)
#pragma unroll
    for (int j = 0; j < 4; ++j) acc[i][j] = fz;

  stageW(0, 0);
  loadX(0);
  for (int cc = 0; cc < 4; ++cc) {
    __syncthreads();                 // drains W(cc) glds; Xs WAR safe
#pragma unroll
    for (int p = 0; p < 4; ++p) {
      int cb4 = p * 16 + wv * 4;
      int swz = (((cb4 >> 3) ^ (lane >> 3)) << 3) | (cb4 & 7);
      ushort4 s4;
      s4.x = f2bf(xr[p * 4 + 0]); s4.y = f2bf(xr[p * 4 + 1]);
      s4.z = f2bf(xr[p * 4 + 2]); s4.w = f2bf(xr[p * 4 + 3]);
      *(ushort4*)&Xs[lane * 72 + swz] = s4;
    }
    if (cc < 3) { stageW(cc + 1, (cc + 1) & 1); loadX(cc + 1); }
    __syncthreads();                 // Xs visible
    const unsigned short* Wc = Wb[cc & 1];
#pragma unroll
    for (int kk = 0; kk < 2; ++kk) {
      int cb = kk * 4 + quad;
      bf16x8 af[2], bfv[4];
#pragma unroll
      for (int mt = 0; mt < 2; ++mt)
        af[mt] = *(const bf16x8*)&Wc[(((wv * 2 + mt) * 8 + cb) * 16 + m) * 8];
#pragma unroll
      for (int nt = 0; nt < 4; ++nt) {
        int t = nt * 16 + m;
        bfv[nt] = *(const bf16x8*)&Xs[t * 72 + ((cb ^ (t >> 3)) << 3)];
      }
#pragma unroll
      for (int mt = 0; mt < 2; ++mt)
#pragma unroll
        for (int nt = 0; nt < 4; ++nt)
          acc[mt][nt] = __builtin_amdgcn_mfma_f32_16x16x32_bf16(af[mt], bfv[nt], acc[mt][nt], 0, 0, 0);
    }
  }

  // epilogue. D layout: row (oc) = quad*4+r, col (t) = m
  if (gid == 0) {
#pragma unroll
    for (int mt = 0; mt < 2; ++mt)
#pragma unroll
      for (int nt = 0; nt < 4; ++nt) {
        int ocl = wv * 32 + mt * 16 + quad * 4;
        int t = t0 + nt * 16 + m;
        ushort4 s4;
        s4.x = f2bf(fmaxf(acc[mt][nt][0] + effbs[ocl + 0], 0.f));
        s4.y = f2bf(fmaxf(acc[mt][nt][1] + effbs[ocl + 1], 0.f));
        s4.z = f2bf(fmaxf(acc[mt][nt][2] + effbs[ocl + 2], 0.f));
        s4.w = f2bf(fmaxf(acc[mt][nt][3] + effbs[ocl + 3], 0.f));
        if (ocl < 64) {
          int col = (((ocl >> 3) ^ (t & 7)) << 3) | (ocl & 7);
          *(ushort4*)(kTs + ((size_t)(b * TDIM + t)) * 64 + col) = s4;
        } else {
          int oq = ocl - 64;
          int col = (((oq >> 3) ^ (t & 7)) << 3) | (oq & 7);
          *(ushort4*)(qTs + ((size_t)(b * TDIM + t)) * 64 + col) = s4;
        }
      }
  } else {
#pragma unroll
    for (int mt = 0; mt < 2; ++mt)
#pragma unroll
      for (int nt = 0; nt < 4; ++nt)
#pragma unroll
        for (int r = 0; r < 4; ++r) {
          int ocl = wv * 32 + mt * 16 + quad * 4 + r;
          float y = fmaxf(acc[mt][nt][r] + effbs[ocl], 0.f);
          int c = (gid - 1) * 128 + ocl;
          int t = t0 + nt * 16 + m;
          vv[(size_t)(b * 256 + c) * TDIM + t] = f2bf(y);
        }
  }
}

// ---------------------------------------------------------------------------
// K2: batch-0 row denominators (the reference's [0]-broadcast bug).
// grid 128 (16 rows each), block 512 (8 waves split the 17 s-tiles).
// ---------------------------------------------------------------------------
__global__ __launch_bounds__(512, 1) void k_denom(
    const unsigned short* __restrict__ kTs,
    const unsigned short* __restrict__ qTs,
    float* __restrict__ denom0)
{
  const int t0d = blockIdx.x * 16;
  const int tid = threadIdx.x;
  const int lane = tid & 63, w = tid >> 6;
  const int m = lane & 15, quad = lane >> 4;

  __shared__ unsigned short S[18432];     // Qs 16x64 | Ks 272x64
  unsigned short* Qs = S;
  unsigned short* Ks = S + 1024;
  __shared__ float pmaxs[8][16];
  __shared__ float psums[8][16];

  {
    const unsigned short* qg = qTs + (size_t)t0d * 64;
    const unsigned short* kg = kTs + ((long)t0d - 256) * 64;  // finite garbage, masked
#pragma unroll
    for (int it = 0; it < 5; ++it) {
      int j = it * 512 + tid;
      if (j < 2304) {
        const unsigned short* g = (j < 128) ? (qg + j * 8) : (kg + (size_t)(j - 128) * 8);
        gl_lds16(g, &S[(it * 512 + w * 64) * 8]);
      }
    }
  }
  __syncthreads();

  const int jn = (w == 0) ? 3 : 2;
  f32x4 sc[3];
  {
    int t = m;
    bf16x8 qf0 = *(const bf16x8*)&Qs[t * 64 + ((quad ^ (t & 7)) << 3)];
    bf16x8 qf1 = *(const bf16x8*)&Qs[t * 64 + (((4 + quad) ^ (t & 7)) << 3)];
    const f32x4 fz = {0.f, 0.f, 0.f, 0.f};
#pragma unroll
    for (int jj = 0; jj < 3; ++jj) {
      if (jj < jn) {
        int j = w + jj * 8;
        int sr = 16 * j + m;
        f32x4 a = fz;
        bf16x8 kf0 = *(const bf16x8*)&Ks[sr * 64 + ((quad ^ (sr & 7)) << 3)];
        a = __builtin_amdgcn_mfma_f32_16x16x32_bf16(qf0, kf0, a, 0, 0, 0);
        bf16x8 kf1 = *(const bf16x8*)&Ks[sr * 64 + (((4 + quad) ^ (sr & 7)) << 3)];
        a = __builtin_amdgcn_mfma_f32_16x16x32_bf16(qf1, kf1, a, 0, 0, 0);
        sc[jj] = a;
      }
    }
  }

  float mx[4] = {0.f, 0.f, 0.f, 0.f};
#pragma unroll
  for (int jj = 0; jj < 3; ++jj)
    if (jj < jn) {
      int j = w + jj * 8;
#pragma unroll
      for (int r = 0; r < 4; ++r) {
        float v = sc[jj][r] * 0.125f;
        sc[jj][r] = v;
        int tg = t0d + quad * 4 + r;
        int sg = t0d - 256 + 16 * j + m;
        if (sg >= 0 && sg <= tg && tg - sg < 256) mx[r] = fmaxf(mx[r], v);
      }
    }
#pragma unroll
  for (int d = 1; d < 16; d <<= 1)
#pragma unroll
    for (int r = 0; r < 4; ++r) mx[r] = fmaxf(mx[r], __shfl_xor(mx[r], d, 64));
  if (m == 0)
#pragma unroll
    for (int r = 0; r < 4; ++r) pmaxs[w][quad * 4 + r] = mx[r];
  __syncthreads();

  float mxf[4];
#pragma unroll
  for (int r = 0; r < 4; ++r) {
    float v = pmaxs[0][quad * 4 + r];
#pragma unroll
    for (int ww = 1; ww < 8; ++ww) v = fmaxf(v, pmaxs[ww][quad * 4 + r]);
    mxf[r] = v;
  }
  float sm[4] = {0.f, 0.f, 0.f, 0.f};
#pragma unroll
  for (int jj = 0; jj < 3; ++jj)
    if (jj < jn) {
      int j = w + jj * 8;
#pragma unroll
      for (int r = 0; r < 4; ++r) {
        int tg = t0d + quad * 4 + r;
        int sg = t0d - 256 + 16 * j + m;
        if (sg >= 0 && sg <= tg && tg - sg < 256) sm[r] += __expf(sc[jj][r] - mxf[r]);
      }
    }
#pragma unroll
  for (int d = 1; d < 16; d <<= 1)
#pragma unroll
    for (int r = 0; r < 4; ++r) sm[r] += __shfl_xor(sm[r], d, 64);
  if (m == 0)
#pragma unroll
    for (int r = 0; r < 4; ++r) psums[w][quad * 4 + r] = sm[r];
  __syncthreads();

  if (tid < 16) {
    float s = 0.f;
#pragma unroll
    for (int ww = 0; ww < 8; ++ww) s += psums[ww][tid];
    denom0[t0d + tid] = s;
  }
}

// ---------------------------------------------------------------------------
// K3: banded attention + residual, MERGED channels.
// grid (32 tb-swizzled, 8 b) = 256 wgs, block 512 (8 waves). Score computed
// ONCE per tile; PV gives each wave a 32-c strip (P A-frag reused for both
// c-tiles). XCD swizzle: consecutive tb share an XCD for V-band L2 reuse.
// ---------------------------------------------------------------------------
__global__ __launch_bounds__(512, 2) void k_attn(
    const float* __restrict__ x,
    const unsigned short* __restrict__ vv,
    const unsigned short* __restrict__ kTs,
    const unsigned short* __restrict__ qTs,
    const float* __restrict__ denom0,
    float* __restrict__ out)
{
  const int bx = blockIdx.x, b = blockIdx.y;
  const int tb = (bx >> 3) + 4 * (bx & 7);   // XCD-aware: same-XCD blocks get adjacent tb
  const int tid = threadIdx.x;
  const int lane = tid & 63, w = tid >> 6;
  const int m = lane & 15, quad = lane >> 4;
  const int t0 = tb * 64;

  // phase 1: Qs 64x64 (4096) + Ks 320x64 (20480); phase 2: Ps 64x344 (22016)
  __shared__ unsigned short SM[24576];
  __shared__ float pmaxs[128];          // [half][row]
  unsigned short* Qs = SM;
  unsigned short* Ks = SM + 4096;
  unsigned short* Ps = SM;

  {
    const unsigned short* qg = qTs + ((size_t)(b * TDIM + t0)) * 64;
    const unsigned short* kg = kTs + ((long)(b * TDIM + t0) - 256) * 64;  // finite garbage, masked
#pragma unroll
    for (int it = 0; it < 6; ++it) {
      int j = it * 512 + tid;
      const unsigned short* g = (j < 512) ? (qg + (size_t)j * 8)
                                          : (kg + (size_t)(j - 512) * 8);
      gl_lds16(g, &SM[(it * 512 + w * 64) * 8]);
    }
  }
  const int rt = w & 3, half = w >> 2;
  const int tw = t0 + rt * 16;
  float dval[4];
#pragma unroll
  for (int r = 0; r < 4; ++r) dval[r] = denom0[tw + quad * 4 + r];
  __syncthreads();                       // B1: staging drained

  const int j0 = half ? 9 : 0;
  const int jn = half ? 8 : 9;
  f32x4 sc[9];
  {
    int t = rt * 16 + m;
    bf16x8 qf0 = *(const bf16x8*)&Qs[t * 64 + ((quad ^ (t & 7)) << 3)];
    bf16x8 qf1 = *(const bf16x8*)&Qs[t * 64 + (((4 + quad) ^ (t & 7)) << 3)];
    const f32x4 fz = {0.f, 0.f, 0.f, 0.f};
#pragma unroll
    for (int jj = 0; jj < 9; ++jj) {
      if (jj < jn) {
        int sr = 16 * (rt + j0 + jj) + m;
        f32x4 a = fz;
        bf16x8 kf0 = *(const bf16x8*)&Ks[sr * 64 + ((quad ^ (sr & 7)) << 3)];
        a = __builtin_amdgcn_mfma_f32_16x16x32_bf16(qf0, kf0, a, 0, 0, 0);
        bf16x8 kf1 = *(const bf16x8*)&Ks[sr * 64 + (((4 + quad) ^ (sr & 7)) << 3)];
        a = __builtin_amdgcn_mfma_f32_16x16x32_bf16(qf1, kf1, a, 0, 0, 0);
        sc[jj] = a;
      }
    }
  }

  float mx[4] = {0.f, 0.f, 0.f, 0.f};
#pragma unroll
  for (int jj = 0; jj < 9; ++jj)
    if (jj < jn) {
#pragma unroll
      for (int r = 0; r < 4; ++r) {
        float v = sc[jj][r] * 0.125f;
        sc[jj][r] = v;
        int tg = tw + quad * 4 + r;
        int sg = t0 - 256 + 16 * (rt + j0 + jj) + m;
        if (sg >= 0 && sg <= tg && tg - sg < 256) mx[r] = fmaxf(mx[r], v);
      }
    }
#pragma unroll
  for (int d = 1; d < 16; d <<= 1)
#pragma unroll
    for (int r = 0; r < 4; ++r) mx[r] = fmaxf(mx[r], __shfl_xor(mx[r], d, 64));
  if (m == 0)
#pragma unroll
    for (int r = 0; r < 4; ++r) pmaxs[half * 64 + rt * 16 + quad * 4 + r] = mx[r];

  __syncthreads();                       // B2: frag reads done + pmax visible

  float mxf[4], rden[4];
#pragma unroll
  for (int r = 0; r < 4; ++r) {
    int row = rt * 16 + quad * 4 + r;
    mxf[r] = fmaxf(pmaxs[row], pmaxs[64 + row]);
    rden[r] = 1.f / (dval[r] + 1e-30f);
  }
#pragma unroll
  for (int jj = 0; jj < 9; ++jj)
    if (jj < jn) {
#pragma unroll
      for (int r = 0; r < 4; ++r) {
        int tg = tw + quad * 4 + r;
        int sg = t0 - 256 + 16 * (rt + j0 + jj) + m;
        bool ib = (sg >= 0 && sg <= tg && tg - sg < 256);
        sc[jj][r] = ib ? __expf(sc[jj][r] - mxf[r]) * rden[r] : 0.f;
      }
    }

  // zero PADS: rows [rt*16,+16), 16 cols just outside this row-tile's window
  if (half == 0) {
    if (rt > 0) {
      int row = rt * 16 + (lane >> 2), col = 16 * rt - 16 + (lane & 3) * 4;
      ushort4 z; z.x = 0; z.y = 0; z.z = 0; z.w = 0;
      *(ushort4*)&Ps[row * 344 + col] = z;
    }
  } else {
    if (rt < 3) {
      int row = rt * 16 + (lane >> 2), col = 16 * rt + 272 + (lane & 3) * 4;
      ushort4 z; z.x = 0; z.y = 0; z.z = 0; z.w = 0;
      *(ushort4*)&Ps[row * 344 + col] = z;
    }
  }
  // scatter normalized P (rows rt*16+quad*4+r, cols 16*(rt+j)+m)
#pragma unroll
  for (int jj = 0; jj < 9; ++jj)
    if (jj < jn) {
      int col = 16 * (rt + j0 + jj) + m;
#pragma unroll
      for (int r = 0; r < 4; ++r)
        Ps[(rt * 16 + quad * 4 + r) * 344 + col] = f2bf(sc[jj][r]);
    }

  // V chunk-0 prefetch (both c-tiles) issued before the barrier
  const int cbase = w * 32;
  const unsigned short* vrow0 = vv + (size_t)(b * 256 + cbase + m) * TDIM;
  const unsigned short* vrow1 = vrow0 + (size_t)16 * TDIM;
  us8 vreg0 = {0, 0, 0, 0, 0, 0, 0, 0}, vreg1 = {0, 0, 0, 0, 0, 0, 0, 0};
  if (t0 >= 256) {
    vreg0 = *(const us8*)(vrow0 + t0 - 256 + quad * 8);
    vreg1 = *(const us8*)(vrow1 + t0 - 256 + quad * 8);
  }

  __syncthreads();                       // B3: P visible

  // x-residual prefetch (overlaps PV)
  float4 xv[4][2];
#pragma unroll
  for (int mt = 0; mt < 4; ++mt)
#pragma unroll
    for (int ct = 0; ct < 2; ++ct) {
      int c = cbase + ct * 16 + m;
      int t = t0 + mt * 16 + quad * 4;
      xv[mt][ct] = *(const float4*)(x + (size_t)(b * 256 + c) * TDIM + t);
    }

  // ---- PV: 10 V chunks; row-tile mt uses window [mt>>1, mt>>1 + 8] ----
  const f32x4 fz = {0.f, 0.f, 0.f, 0.f};
  f32x4 acc[4][2];
#pragma unroll
  for (int i = 0; i < 4; ++i) { acc[i][0] = fz; acc[i][1] = fz; }
#pragma unroll
  for (int chunk = 0; chunk < 10; ++chunk) {
    us8 vn0 = {0, 0, 0, 0, 0, 0, 0, 0}, vn1 = {0, 0, 0, 0, 0, 0, 0, 0};
    if (chunk < 9) {
      int sbase = t0 - 256 + (chunk + 1) * 32;
      if (sbase >= 0) {
        vn0 = *(const us8*)(vrow0 + sbase + quad * 8);
        vn1 = *(const us8*)(vrow1 + sbase + quad * 8);
      }
    }
    bf16x8 bfr0 = __builtin_bit_cast(bf16x8, vreg0);
    bf16x8 bfr1 = __builtin_bit_cast(bf16x8, vreg1);
#pragma unroll
    for (int mt = 0; mt < 4; ++mt) {
      const int cs = mt >> 1;
      if (chunk >= cs && chunk <= cs + 8) {
        bf16x8 af = *(const bf16x8*)&Ps[(mt * 16 + m) * 344 + chunk * 32 + quad * 8];
        acc[mt][0] = __builtin_amdgcn_mfma_f32_16x16x32_bf16(af, bfr0, acc[mt][0], 0, 0, 0);
        acc[mt][1] = __builtin_amdgcn_mfma_f32_16x16x32_bf16(af, bfr1, acc[mt][1], 0, 0, 0);
      }
    }
    vreg0 = vn0; vreg1 = vn1;
  }

  // epilogue: out = x + O^T.  D: col (c) = m, row (t) = quad*4+r
#pragma unroll
  for (int mt = 0; mt < 4; ++mt)
#pragma unroll
    for (int ct = 0; ct < 2; ++ct) {
      int c = cbase + ct * 16 + m;
      int t = t0 + mt * 16 + quad * 4;
      size_t off = (size_t)(b * 256 + c) * TDIM + t;
      float4 o;
      o.x = xv[mt][ct].x + acc[mt][ct][0];
      o.y = xv[mt][ct].y + acc[mt][ct][1];
      o.z = xv[mt][ct].z + acc[mt][ct][2];
      o.w = xv[mt][ct].w + acc[mt][ct][3];
      *(float4*)(out + off) = o;
    }
}

// ---------------------------------------------------------------------------
extern "C" void kernel_launch(void* const* d_in, const int* in_sizes, int n_in,
                              void* d_out, int out_size, void* d_ws, size_t ws_size,
                              hipStream_t stream) {
  const float* x   = (const float*)d_in[0];
  const float* kW  = (const float*)d_in[1];
  const float* kb  = (const float*)d_in[2];
  const float* kg  = (const float*)d_in[3];
  const float* kbe = (const float*)d_in[4];
  const float* kmu = (const float*)d_in[5];
  const float* kva = (const float*)d_in[6];
  const float* qW  = (const float*)d_in[7];
  const float* qb  = (const float*)d_in[8];
  const float* qg  = (const float*)d_in[9];
  const float* qbe = (const float*)d_in[10];
  const float* qmu = (const float*)d_in[11];
  const float* qva = (const float*)d_in[12];
  const float* vW  = (const float*)d_in[13];
  const float* vb  = (const float*)d_in[14];
  const float* vg  = (const float*)d_in[15];
  const float* vbe = (const float*)d_in[16];
  const float* vmu = (const float*)d_in[17];
  const float* vva = (const float*)d_in[18];

  unsigned short* vv  = (unsigned short*)d_ws;                  // 8 MB
  unsigned short* kTs = vv + (size_t)8 * 256 * TDIM;            // 2 MB
  unsigned short* qTs = kTs + (size_t)8 * TDIM * 64;            // 2 MB
  float* denom0 = (float*)(qTs + (size_t)8 * TDIM * 64);        // 8 KB
  unsigned short* effWf = (unsigned short*)(denom0 + 2048);     // 192 KB
  float* effb = (float*)(effWf + 12 * 8192);                    // 1.5 KB
  float* outp = (float*)d_out;

  k_prepw<<<dim3(12), 256, 0, stream>>>(
      kW, kb, kg, kbe, kmu, kva,
      qW, qb, qg, qbe, qmu, qva,
      vW, vb, vg, vbe, vmu, vva, effWf, effb);
  k_qkv<<<dim3(32, 3, 8), 256, 0, stream>>>(effWf, effb, x, vv, kTs, qTs);
  k_denom<<<dim3(128), 512, 0, stream>>>(kTs, qTs, denom0);
  k_attn<<<dim3(32, 8), 512, 0, stream>>>(x, vv, kTs, qTs, denom0, outp);
}